// Round 16
// baseline (751.198 us; speedup 1.0000x reference)
//
#include <hip/hip_runtime.h>

// Dims fixed: N=100000, E=1600000, ND=16, ED=1, HD=64, OD=1; feat ch = 17.
//
// Algebra:
//  - W2 commutes with the weighted segment-sum -> applied once per NODE.
//  - VN_ReLU(w*m) = w*VN_ReLU(m), w>0          -> nw folded into X1w precompute.
//  - d = Wd@m linear                            -> d = D1w[src] + s*(w*ea).
// Round-13 profile: node_k LATENCY-bound (FETCH halved 893->567MB, dur flat
// 411->405us; 155 cyc/edge/CU). Fix: wave-local LDS staging of each 32-edge
// chunk's X1w data (12 independent uint4 loads/lane -> deep MLP), phase B
// consumes from LDS. No barriers (wave-synchronous).
//
// ws (4B words): X1w[N*96 (ushort N*192)] | D1w[N*3] | s[1] | cnt[N] | gctr[1] | off[N] | cur[N] | eidx[E]

__device__ __forceinline__ float rl_f(float v, int l) {
    return __int_as_float(__builtin_amdgcn_readlane(__float_as_int(v), l));
}
__device__ __forceinline__ unsigned short f2bf(float f) {   // RNE f32->bf16
    unsigned u = __float_as_uint(f);
    return (unsigned short)((u + 0x7FFFu + ((u >> 16) & 1u)) >> 16);
}
__device__ __forceinline__ float bf2f(unsigned short h) {
    return __uint_as_float((unsigned)h << 16);
}

// Fused: per-node X1w/D1w precompute + edge count histogram.
__global__ __launch_bounds__(256) void x1c_k(
    const float* __restrict__ x, const float* __restrict__ nw,
    const float* __restrict__ W1, const float* __restrict__ Wd,
    const int* __restrict__ ei,
    unsigned short* __restrict__ X1w, float* __restrict__ D1w, float* __restrict__ sW,
    int* __restrict__ cnt,
    int N, int E, int nthreads)
{
    const int lane = threadIdx.x & 63;
    const int tid  = blockIdx.x * blockDim.x + threadIdx.x;
    const int wave = tid >> 6;
    const int nwaves = nthreads >> 6;

    float w1[16];
#pragma unroll
    for (int c = 0; c < 16; ++c) w1[c] = W1[lane * 17 + c];
    const float wd = Wd[lane];

    if (wave == 0) {                       // s = sum_o Wd[o]*W1[o][16]
        float t = wd * W1[lane * 17 + 16];
#pragma unroll
        for (int off = 32; off; off >>= 1) t += __shfl_xor(t, off);
        if (lane == 0) sW[0] = t;
    }

    for (int n = wave; n < N; n += nwaves) {
        const int nu = __builtin_amdgcn_readfirstlane(n);
        const float* xp = x + (size_t)nu * 48;
        const float wn = nw[nu];
        float h0 = 0.f, h1 = 0.f, h2 = 0.f;
#pragma unroll
        for (int c = 0; c < 16; ++c) {
            h0 = fmaf(w1[c], xp[c * 3 + 0], h0);
            h1 = fmaf(w1[c], xp[c * 3 + 1], h1);
            h2 = fmaf(w1[c], xp[c * 3 + 2], h2);
        }
        h0 *= wn; h1 *= wn; h2 *= wn;
        unsigned short* op = X1w + (size_t)nu * 192;
        op[lane] = f2bf(h0); op[64 + lane] = f2bf(h1); op[128 + lane] = f2bf(h2);

        float t0 = wd * h0, t1 = wd * h1, t2 = wd * h2;   // D1w stays f32
#pragma unroll
        for (int off = 32; off; off >>= 1) {
            t0 += __shfl_xor(t0, off); t1 += __shfl_xor(t1, off); t2 += __shfl_xor(t2, off);
        }
        if (lane == 0) {
            float* dp = D1w + (size_t)nu * 3;
            dp[0] = t0; dp[1] = t1; dp[2] = t2;
        }
    }

    // fused edge-count histogram (independent of the node loop above)
    for (int e = tid; e < E; e += nthreads)
        atomicAdd(&cnt[ei[E + e]], 1);
}

// Order-free exclusive "scan": wave-uniform loop (lane 63 always active).
__global__ __launch_bounds__(256) void scan_k(
    const int* __restrict__ cnt, int* __restrict__ off, int* __restrict__ cur,
    int* __restrict__ gctr, int N, int stride)
{
    const int lane = threadIdx.x & 63;
    const int tid  = blockIdx.x * blockDim.x + threadIdx.x;
    for (int nb = tid - lane; nb < N; nb += stride) {
        const int n = nb + lane;
        const int v = (n < N) ? cnt[n] : 0;
        int incl = v;
#pragma unroll
        for (int d = 1; d < 64; d <<= 1) {
            const int t = __shfl_up(incl, d);
            if (lane >= d) incl += t;
        }
        const int tot = __builtin_amdgcn_readlane(incl, 63);
        int base = 0;
        if (lane == 63) base = atomicAdd(gctr, tot);
        base = __builtin_amdgcn_readlane(base, 63);
        if (n < N) {
            const int o = base + incl - v;
            off[n] = o; cur[n] = o;
        }
    }
}

__global__ __launch_bounds__(256) void fill_k(
    const int* __restrict__ ei, int* __restrict__ cur, int* __restrict__ eidx,
    int E, int stride)
{
    for (int e = blockIdx.x * blockDim.x + threadIdx.x; e < E; e += stride) {
        const int slot = atomicAdd(&cur[ei[E + e]], 1);
        eidx[slot] = e;
    }
}

// One wave per node. Per <=32-edge chunk:
//  phase A (parallel): lane j (j<32) loads edge j's meta, computes unit dir u, sj->LDS.
//  stage: 12 independent uint4 loads/lane pull the chunk's X1w rows into LDS
//         (unit u -> edge u/24, 16B slot u%24; deep MLP, latency exposed once/chunk).
//  phase B (broadcast): per edge, readlane(meta) + 3 ds_read_u16 from LDS + VN-ReLU.
__global__ __launch_bounds__(256) void node_k(
    const int* __restrict__ ei, const float* __restrict__ ea,
    const float* __restrict__ nw,  const float* __restrict__ W1,
    const unsigned short* __restrict__ X1w, const float* __restrict__ D1w,
    const float* __restrict__ sW,
    const int* __restrict__ off, const int* __restrict__ cnt,
    const int* __restrict__ eidx,
    const float* __restrict__ W2,  const float* __restrict__ Wo1,
    const float* __restrict__ bo1, const float* __restrict__ Wo2,
    const float* __restrict__ bo2, float* __restrict__ out,
    int N, int nwaves)
{
    __shared__ uint4 xst[4][768];          // 32 edges x 384B per wave slot (48KB)
    __shared__ int   sjl[4][32];

    const int wave  = (blockIdx.x * blockDim.x + threadIdx.x) >> 6;
    const int lane  = threadIdx.x & 63;
    const int wslot = (threadIdx.x >> 6) & 3;
    const unsigned short* xsh = (const unsigned short*)xst[wslot];

    const float s   = sW[0];
    const float w16 = W1[lane * 17 + 16];   // W1[:,16]; lane owns channel `lane`
    const float b1  = bo1[lane];
    const float wo2 = Wo2[lane];
    const float b2  = bo2[0];

    for (int n = wave; n < N; n += nwaves) {
        const int nu  = __builtin_amdgcn_readfirstlane(n);
        const int p0  = __builtin_amdgcn_readfirstlane(off[nu]);
        const int deg = __builtin_amdgcn_readfirstlane(cnt[nu]);

        float h0 = 0.f, h1 = 0.f, h2 = 0.f, wsum = 0.f;

        for (int p = p0; p < p0 + deg; p += 32) {
            const int kcnt = min(32, p0 + deg - p);

            // --- phase A: one edge per lane (lanes 0..kcnt-1); regs zeroed for
            //     ALL lanes so phase-B readlane is well-defined ---
            int   src = 0;
            float we0 = 0.f, we1 = 0.f, we2 = 0.f, u0 = 0.f, u1 = 0.f, u2 = 0.f;
            if (lane < kcnt) {
                const int e = eidx[p + lane];
                src = ei[e];
                sjl[wslot][lane] = src;
                const float w = nw[src];
                const float* eap = ea + (size_t)e * 3;
                we0 = w * eap[0]; we1 = w * eap[1]; we2 = w * eap[2];
                const float* d1p = D1w + (size_t)src * 3;
                const float d0 = fmaf(s, we0, d1p[0]);
                const float d1 = fmaf(s, we1, d1p[1]);
                const float d2 = fmaf(s, we2, d1p[2]);
                const float dd = fmaf(d2, d2, fmaf(d1, d1, d0 * d0));
                const float inv = 1.0f / sqrtf(dd);   // dd==0 -> NaN dir (w==0), matches ref
                u0 = d0 * inv; u1 = d1 * inv; u2 = d2 * inv;
                wsum += w;
            }

            // --- stage: chunk's X1w rows -> LDS via 12 independent 16B loads/lane ---
#pragma unroll
            for (int i = 0; i < 12; ++i) {
                const int u  = i * 64 + lane;      // 16B unit id in [0,768)
                const int eu = u / 24;              // owning edge (24 units/edge)
                uint4 v = uint4{0u, 0u, 0u, 0u};
                if (eu < kcnt) {
                    const int sje = sjl[wslot][eu];
                    const uint4* gp = (const uint4*)(X1w + (size_t)sje * 192) + (u - eu * 24);
                    v = *gp;
                }
                xst[wslot][u] = v;
            }

            // --- phase B: broadcast + LDS reads + VN-ReLU ---
            for (int j = 0; j < kcnt; ++j) {
                const float a0 = rl_f(we0, j), a1 = rl_f(we1, j), a2 = rl_f(we2, j);
                const float v0 = rl_f(u0, j),  v1 = rl_f(u1, j),  v2 = rl_f(u2, j);
                const unsigned short* xb = xsh + j * 192 + lane;
                float m0 = fmaf(w16, a0, bf2f(xb[0]));
                float m1 = fmaf(w16, a1, bf2f(xb[64]));
                float m2 = fmaf(w16, a2, bf2f(xb[128]));
                const float dpv = fmaf(m2, v2, fmaf(m1, v1, m0 * v0));
                if (!(dpv >= 0.f)) {                   // also taken when dpv is NaN
                    m0 = fmaf(-dpv, v0, m0); m1 = fmaf(-dpv, v1, m1); m2 = fmaf(-dpv, v2, m2);
                }
                h0 += m0; h1 += m1; h2 += m2;
            }
        }

        float den = wsum;
#pragma unroll
        for (int o = 32; o; o >>= 1) den += __shfl_xor(den, o);

        const float invd = 1.0f / (den > 0.f ? den : 1.0f);
        const float hp0 = h0 * invd, hp1 = h1 * invd, hp2 = h2 * invd;

        // g[o] = sum_c W2[o][c]*hp[c][v]; W2 row streamed as float4 (L1-resident)
        float g0 = 0.f, g1 = 0.f, g2 = 0.f;
        const float4* w2r = (const float4*)(W2 + lane * 64);
#pragma unroll
        for (int c4 = 0; c4 < 16; ++c4) {
            const float4 wv = w2r[c4];
#pragma unroll
            for (int j = 0; j < 4; ++j) {
                const int c = c4 * 4 + j;
                const float wc = j == 0 ? wv.x : j == 1 ? wv.y : j == 2 ? wv.z : wv.w;
                g0 = fmaf(wc, rl_f(hp0, c), g0);
                g1 = fmaf(wc, rl_f(hp1, c), g1);
                g2 = fmaf(wc, rl_f(hp2, c), g2);
            }
        }
        const float hinv = sqrtf(fmaf(g2, g2, fmaf(g1, g1, g0 * g0)) + 1e-12f);

        float acc = b1;
        const float4* wo1r = (const float4*)(Wo1 + lane * 64);
#pragma unroll
        for (int c4 = 0; c4 < 16; ++c4) {
            const float4 wv = wo1r[c4];
#pragma unroll
            for (int j = 0; j < 4; ++j) {
                const int c = c4 * 4 + j;
                const float wc = j == 0 ? wv.x : j == 1 ? wv.y : j == 2 ? wv.z : wv.w;
                acc = fmaf(wc, rl_f(hinv, c), acc);
            }
        }
        const float hid = fmaxf(acc, 0.f);

        float t = wo2 * hid;
#pragma unroll
        for (int o = 32; o; o >>= 1) t += __shfl_xor(t, o);
        if (lane == 0) out[nu] = t + b2;
    }
}

extern "C" void kernel_launch(void* const* d_in, const int* in_sizes, int n_in,
                              void* d_out, int out_size, void* d_ws, size_t ws_size,
                              hipStream_t stream) {
    const float* x   = (const float*)d_in[0];
    const int*   ei  = (const int*)d_in[1];     // int32 (JAX x64 disabled)
    const float* ea  = (const float*)d_in[2];
    const float* nw  = (const float*)d_in[3];
    const float* W1  = (const float*)d_in[4];
    const float* Wd  = (const float*)d_in[5];
    const float* W2  = (const float*)d_in[6];
    const float* Wo1 = (const float*)d_in[7];
    const float* bo1 = (const float*)d_in[8];
    const float* Wo2 = (const float*)d_in[9];
    const float* bo2 = (const float*)d_in[10];

    const int N = in_sizes[3];         // node_weight: N
    const int E = in_sizes[2] / 3;     // edge_attr: E x 1 x 3

    // ws words: X1w 96N (ushort 192N) | D1w 3N | s 1 | cnt N | gctr 1 | off N | cur N | eidx E
    const size_t need = ((size_t)N * 102 + (size_t)E + 2) * 4;
    if (ws_size < need) return;

    unsigned short* X1w = (unsigned short*)d_ws;          // N*192 ushorts
    float* D1w = (float*)d_ws + (size_t)N * 96;
    float* sW  = D1w + (size_t)N * 3;
    int*   cnt = (int*)(sW + 1);
    int*   gctr= cnt + N;
    int*   off = gctr + 1;
    int*   cur = off + N;
    int*   eidx= cur + N;

    hipMemsetAsync(cnt, 0, ((size_t)N + 1) * sizeof(int), stream);  // cnt + gctr

    const int blocks = 2048, threads = blocks * 256, waves = threads / 64;
    x1c_k<<<blocks, 256, 0, stream>>>(x, nw, W1, Wd, ei, X1w, D1w, sW, cnt, N, E, threads);
    scan_k<<<256, 256, 0, stream>>>(cnt, off, cur, gctr, N, 256 * 256);
    fill_k<<<blocks, 256, 0, stream>>>(ei, cur, eidx, E, threads);
    node_k<<<blocks, 256, 0, stream>>>(ei, ea, nw, W1, X1w, D1w, sW,
                                       off, cnt, eidx, W2, Wo1, bo1, Wo2, bo2,
                                       (float*)d_out, N, waves);
}

// Round 17
// 722.791 us; speedup vs baseline: 1.0393x; 1.0393x over previous
//
#include <hip/hip_runtime.h>

// Dims fixed: N=100000, E=1600000, ND=16, ED=1, HD=64, OD=1; feat ch = 17.
//
// Algebra:
//  - W2 commutes with the weighted segment-sum -> applied once per NODE.
//  - VN_ReLU(w*m) = w*VN_ReLU(m), w>0          -> nw folded into X1w precompute.
//  - d = Wd@m linear                            -> d = D1w[src] + s*(w*ea).
// Evidence: r9 (f32, 893MB) == r13 (bf16, 567MB) == ~405us -> node_k is bound
// by per-edge load-EVENT serialization, not bytes/lines. r16 LDS staging
// REGRESSED (435us, occ 21.7%) -> reverted.
// This rev: X1w padded to [N][64] ushort4 -> ONE 8B load/lane/edge (was 3),
// plus explicit 1-deep prefetch of edge j+1's load before computing edge j.
//
// ws (4B words): X1w[N*128 (ushort4 N*64)] | D1w[N*3] | s[1] | cnt[N] | gctr[1] | off[N] | cur[N] | eidx[E]

__device__ __forceinline__ float rl_f(float v, int l) {
    return __int_as_float(__builtin_amdgcn_readlane(__float_as_int(v), l));
}
__device__ __forceinline__ unsigned short f2bf(float f) {   // RNE f32->bf16
    unsigned u = __float_as_uint(f);
    return (unsigned short)((u + 0x7FFFu + ((u >> 16) & 1u)) >> 16);
}

// Fused: per-node X1w/D1w precompute + edge count histogram.
// X1w[n][lane] = ushort4{bf(h0), bf(h1), bf(h2), 0} packed as uint2.
__global__ __launch_bounds__(256) void x1c_k(
    const float* __restrict__ x, const float* __restrict__ nw,
    const float* __restrict__ W1, const float* __restrict__ Wd,
    const int* __restrict__ ei,
    uint2* __restrict__ X1w, float* __restrict__ D1w, float* __restrict__ sW,
    int* __restrict__ cnt,
    int N, int E, int nthreads)
{
    const int lane = threadIdx.x & 63;
    const int tid  = blockIdx.x * blockDim.x + threadIdx.x;
    const int wave = tid >> 6;
    const int nwaves = nthreads >> 6;

    float w1[16];
#pragma unroll
    for (int c = 0; c < 16; ++c) w1[c] = W1[lane * 17 + c];
    const float wd = Wd[lane];

    if (wave == 0) {                       // s = sum_o Wd[o]*W1[o][16]
        float t = wd * W1[lane * 17 + 16];
#pragma unroll
        for (int off = 32; off; off >>= 1) t += __shfl_xor(t, off);
        if (lane == 0) sW[0] = t;
    }

    for (int n = wave; n < N; n += nwaves) {
        const int nu = __builtin_amdgcn_readfirstlane(n);
        const float* xp = x + (size_t)nu * 48;
        const float wn = nw[nu];
        float h0 = 0.f, h1 = 0.f, h2 = 0.f;
#pragma unroll
        for (int c = 0; c < 16; ++c) {
            h0 = fmaf(w1[c], xp[c * 3 + 0], h0);
            h1 = fmaf(w1[c], xp[c * 3 + 1], h1);
            h2 = fmaf(w1[c], xp[c * 3 + 2], h2);
        }
        h0 *= wn; h1 *= wn; h2 *= wn;
        uint2 q;
        q.x = (unsigned)f2bf(h0) | ((unsigned)f2bf(h1) << 16);
        q.y = (unsigned)f2bf(h2);
        X1w[(size_t)nu * 64 + lane] = q;

        float t0 = wd * h0, t1 = wd * h1, t2 = wd * h2;   // D1w stays f32
#pragma unroll
        for (int off = 32; off; off >>= 1) {
            t0 += __shfl_xor(t0, off); t1 += __shfl_xor(t1, off); t2 += __shfl_xor(t2, off);
        }
        if (lane == 0) {
            float* dp = D1w + (size_t)nu * 3;
            dp[0] = t0; dp[1] = t1; dp[2] = t2;
        }
    }

    // fused edge-count histogram (independent of the node loop above)
    for (int e = tid; e < E; e += nthreads)
        atomicAdd(&cnt[ei[E + e]], 1);
}

// Order-free exclusive "scan": wave-uniform loop (lane 63 always active).
__global__ __launch_bounds__(256) void scan_k(
    const int* __restrict__ cnt, int* __restrict__ off, int* __restrict__ cur,
    int* __restrict__ gctr, int N, int stride)
{
    const int lane = threadIdx.x & 63;
    const int tid  = blockIdx.x * blockDim.x + threadIdx.x;
    for (int nb = tid - lane; nb < N; nb += stride) {
        const int n = nb + lane;
        const int v = (n < N) ? cnt[n] : 0;
        int incl = v;
#pragma unroll
        for (int d = 1; d < 64; d <<= 1) {
            const int t = __shfl_up(incl, d);
            if (lane >= d) incl += t;
        }
        const int tot = __builtin_amdgcn_readlane(incl, 63);
        int base = 0;
        if (lane == 63) base = atomicAdd(gctr, tot);
        base = __builtin_amdgcn_readlane(base, 63);
        if (n < N) {
            const int o = base + incl - v;
            off[n] = o; cur[n] = o;
        }
    }
}

__global__ __launch_bounds__(256) void fill_k(
    const int* __restrict__ ei, int* __restrict__ cur, int* __restrict__ eidx,
    int E, int stride)
{
    for (int e = blockIdx.x * blockDim.x + threadIdx.x; e < E; e += stride) {
        const int slot = atomicAdd(&cur[ei[E + e]], 1);
        eidx[slot] = e;
    }
}

// One wave per node. Per <=64-edge chunk:
//  phase A (parallel): lane j loads edge j's meta and computes its unit direction u.
//  phase B (broadcast): per edge ONE 8B X1w load/lane, software-prefetched one
//  edge ahead so consumption never waits on the just-issued load.
__global__ __launch_bounds__(256) void node_k(
    const int* __restrict__ ei, const float* __restrict__ ea,
    const float* __restrict__ nw,  const float* __restrict__ W1,
    const uint2* __restrict__ X1w, const float* __restrict__ D1w,
    const float* __restrict__ sW,
    const int* __restrict__ off, const int* __restrict__ cnt,
    const int* __restrict__ eidx,
    const float* __restrict__ W2,  const float* __restrict__ Wo1,
    const float* __restrict__ bo1, const float* __restrict__ Wo2,
    const float* __restrict__ bo2, float* __restrict__ out,
    int N, int nwaves)
{
    const int wave = (blockIdx.x * blockDim.x + threadIdx.x) >> 6;
    const int lane = threadIdx.x & 63;

    const float s   = sW[0];
    const float w16 = W1[lane * 17 + 16];   // W1[:,16]; lane owns channel `lane`
    const float b1  = bo1[lane];
    const float wo2 = Wo2[lane];
    const float b2  = bo2[0];

    for (int n = wave; n < N; n += nwaves) {
        const int nu  = __builtin_amdgcn_readfirstlane(n);
        const int p0  = __builtin_amdgcn_readfirstlane(off[nu]);
        const int deg = __builtin_amdgcn_readfirstlane(cnt[nu]);

        float h0 = 0.f, h1 = 0.f, h2 = 0.f, wsum = 0.f;

        for (int p = p0; p < p0 + deg; p += 64) {
            const int kcnt = min(64, p0 + deg - p);

            // --- phase A: one edge per lane (regs zeroed for ALL lanes so
            //     phase-B readlane of inactive lanes is well-defined) ---
            int   src = 0;
            float we0 = 0.f, we1 = 0.f, we2 = 0.f, u0 = 0.f, u1 = 0.f, u2 = 0.f;
            if (lane < kcnt) {
                const int e = eidx[p + lane];
                src = ei[e];
                const float w = nw[src];
                const float* eap = ea + (size_t)e * 3;
                we0 = w * eap[0]; we1 = w * eap[1]; we2 = w * eap[2];
                const float* d1p = D1w + (size_t)src * 3;
                const float d0 = fmaf(s, we0, d1p[0]);
                const float d1 = fmaf(s, we1, d1p[1]);
                const float d2 = fmaf(s, we2, d1p[2]);
                const float dd = fmaf(d2, d2, fmaf(d1, d1, d0 * d0));
                const float inv = 1.0f / sqrtf(dd);   // dd==0 -> NaN dir (w==0), matches ref
                u0 = d0 * inv; u1 = d1 * inv; u2 = d2 * inv;
                wsum += w;
            }

            // --- phase B: 1-deep prefetched 8B gather + VN-ReLU ---
            int  sj0 = __builtin_amdgcn_readlane(src, 0);
            uint2 xv = X1w[(size_t)sj0 * 64 + lane];
            for (int j = 0; j < kcnt; ++j) {
                const int   jn  = (j + 1 < kcnt) ? (j + 1) : (kcnt - 1);
                const int   sjn = __builtin_amdgcn_readlane(src, jn);
                const uint2 xn  = X1w[(size_t)sjn * 64 + lane];   // prefetch next edge

                const float a0 = rl_f(we0, j), a1 = rl_f(we1, j), a2 = rl_f(we2, j);
                const float v0 = rl_f(u0, j),  v1 = rl_f(u1, j),  v2 = rl_f(u2, j);
                const float x0 = __uint_as_float(xv.x << 16);
                const float x1 = __uint_as_float(xv.x & 0xFFFF0000u);
                const float x2 = __uint_as_float(xv.y << 16);
                float m0 = fmaf(w16, a0, x0);
                float m1 = fmaf(w16, a1, x1);
                float m2 = fmaf(w16, a2, x2);
                const float dpv = fmaf(m2, v2, fmaf(m1, v1, m0 * v0));
                if (!(dpv >= 0.f)) {                   // also taken when dpv is NaN
                    m0 = fmaf(-dpv, v0, m0); m1 = fmaf(-dpv, v1, m1); m2 = fmaf(-dpv, v2, m2);
                }
                h0 += m0; h1 += m1; h2 += m2;
                xv = xn;
            }
        }

        float den = wsum;
#pragma unroll
        for (int o = 32; o; o >>= 1) den += __shfl_xor(den, o);

        const float invd = 1.0f / (den > 0.f ? den : 1.0f);
        const float hp0 = h0 * invd, hp1 = h1 * invd, hp2 = h2 * invd;

        // g[o] = sum_c W2[o][c]*hp[c][v]; W2 row streamed as float4 (L1-resident)
        float g0 = 0.f, g1 = 0.f, g2 = 0.f;
        const float4* w2r = (const float4*)(W2 + lane * 64);
#pragma unroll
        for (int c4 = 0; c4 < 16; ++c4) {
            const float4 wv = w2r[c4];
#pragma unroll
            for (int j = 0; j < 4; ++j) {
                const int c = c4 * 4 + j;
                const float wc = j == 0 ? wv.x : j == 1 ? wv.y : j == 2 ? wv.z : wv.w;
                g0 = fmaf(wc, rl_f(hp0, c), g0);
                g1 = fmaf(wc, rl_f(hp1, c), g1);
                g2 = fmaf(wc, rl_f(hp2, c), g2);
            }
        }
        const float hinv = sqrtf(fmaf(g2, g2, fmaf(g1, g1, g0 * g0)) + 1e-12f);

        float acc = b1;
        const float4* wo1r = (const float4*)(Wo1 + lane * 64);
#pragma unroll
        for (int c4 = 0; c4 < 16; ++c4) {
            const float4 wv = wo1r[c4];
#pragma unroll
            for (int j = 0; j < 4; ++j) {
                const int c = c4 * 4 + j;
                const float wc = j == 0 ? wv.x : j == 1 ? wv.y : j == 2 ? wv.z : wv.w;
                acc = fmaf(wc, rl_f(hinv, c), acc);
            }
        }
        const float hid = fmaxf(acc, 0.f);

        float t = wo2 * hid;
#pragma unroll
        for (int o = 32; o; o >>= 1) t += __shfl_xor(t, o);
        if (lane == 0) out[nu] = t + b2;
    }
}

extern "C" void kernel_launch(void* const* d_in, const int* in_sizes, int n_in,
                              void* d_out, int out_size, void* d_ws, size_t ws_size,
                              hipStream_t stream) {
    const float* x   = (const float*)d_in[0];
    const int*   ei  = (const int*)d_in[1];     // int32 (JAX x64 disabled)
    const float* ea  = (const float*)d_in[2];
    const float* nw  = (const float*)d_in[3];
    const float* W1  = (const float*)d_in[4];
    const float* Wd  = (const float*)d_in[5];
    const float* W2  = (const float*)d_in[6];
    const float* Wo1 = (const float*)d_in[7];
    const float* bo1 = (const float*)d_in[8];
    const float* Wo2 = (const float*)d_in[9];
    const float* bo2 = (const float*)d_in[10];

    const int N = in_sizes[3];         // node_weight: N
    const int E = in_sizes[2] / 3;     // edge_attr: E x 1 x 3

    // ws words: X1w 128N (uint2 64N) | D1w 3N | s 1 | cnt N | gctr 1 | off N | cur N | eidx E
    const size_t need = ((size_t)N * 134 + (size_t)E + 2) * 4;
    if (ws_size < need) return;

    uint2* X1w = (uint2*)d_ws;                            // N*64 uint2
    float* D1w = (float*)d_ws + (size_t)N * 128;
    float* sW  = D1w + (size_t)N * 3;
    int*   cnt = (int*)(sW + 1);
    int*   gctr= cnt + N;
    int*   off = gctr + 1;
    int*   cur = off + N;
    int*   eidx= cur + N;

    hipMemsetAsync(cnt, 0, ((size_t)N + 1) * sizeof(int), stream);  // cnt + gctr

    const int blocks = 2048, threads = blocks * 256, waves = threads / 64;
    x1c_k<<<blocks, 256, 0, stream>>>(x, nw, W1, Wd, ei, X1w, D1w, sW, cnt, N, E, threads);
    scan_k<<<256, 256, 0, stream>>>(cnt, off, cur, gctr, N, 256 * 256);
    fill_k<<<blocks, 256, 0, stream>>>(ei, cur, eidx, E, threads);
    node_k<<<blocks, 256, 0, stream>>>(ei, ea, nw, W1, X1w, D1w, sW,
                                       off, cnt, eidx, W2, Wo1, bo1, Wo2, bo2,
                                       (float*)d_out, N, waves);
}